// Round 13
// baseline (285.152 us; speedup 1.0000x reference)
//
#include <hip/hip_runtime.h>
#include <hip/hip_bf16.h>
#include <cstdint>
#include <cstddef>

typedef __attribute__((ext_vector_type(4))) float f32x4;
typedef __attribute__((ext_vector_type(8))) short short8;

#define S_LEN 4096
#define D_DIM 1024
#define H_DIM 1024
#define B_SZ  16
#define M_TOT (B_SZ * S_LEN)  // 65536

// ---------- helpers ----------
__device__ __forceinline__ unsigned short f2bf(float f) {
  unsigned int u = __float_as_uint(f);
  u += 0x7fffu + ((u >> 16) & 1u);
  return (unsigned short)(u >> 16);
}

__device__ __forceinline__ void gload_lds16(void* lds, const void* g) {
  __builtin_amdgcn_global_load_lds(
      (const __attribute__((address_space(1))) unsigned int*)g,
      (__attribute__((address_space(3))) unsigned int*)lds, 16, 0, 0);
}

__device__ __forceinline__ float tanh_fast(float x) {
  return 1.0f - 2.0f / (1.0f + __expf(2.0f * x));
}

// ---------- kernel 0: hs fp32 -> bf16 ----------
__global__ void cvt_hs_kernel(const float* __restrict__ w,
                              unsigned short* __restrict__ o) {
  size_t i = ((size_t)blockIdx.x * 256 + threadIdx.x) * 8;
  float4 v0 = *(const float4*)(w + i);
  float4 v1 = *(const float4*)(w + i + 4);
  union { unsigned short us[8]; short8 v; } pk;
  pk.us[0] = f2bf(v0.x); pk.us[1] = f2bf(v0.y);
  pk.us[2] = f2bf(v0.z); pk.us[3] = f2bf(v0.w);
  pk.us[4] = f2bf(v1.x); pk.us[5] = f2bf(v1.y);
  pk.us[6] = f2bf(v1.z); pk.us[7] = f2bf(v1.w);
  *(short8*)(o + i) = pk.v;
}

// ---------- kernel 1: Ws_w fp32 -> bf16 ----------
__global__ void cvt_w_kernel(const float* __restrict__ w,
                             unsigned short* __restrict__ o) {
  int i = (blockIdx.x * 256 + threadIdx.x) * 8;
  float4 v0 = *(const float4*)(w + i);
  float4 v1 = *(const float4*)(w + i + 4);
  union { unsigned short us[8]; short8 v; } pk;
  pk.us[0] = f2bf(v0.x); pk.us[1] = f2bf(v0.y);
  pk.us[2] = f2bf(v0.z); pk.us[3] = f2bf(v0.w);
  pk.us[4] = f2bf(v1.x); pk.us[5] = f2bf(v1.y);
  pk.us[6] = f2bf(v1.z); pk.us[7] = f2bf(v1.w);
  *(short8*)(o + i) = pk.v;
}

// ---------- kernel 2: c[b,h] ----------
__global__ void prep_c_kernel(const float* __restrict__ ht,
                              const float* __restrict__ hm,
                              const float* __restrict__ Wt_w,
                              const float* __restrict__ Wt_b,
                              const float* __restrict__ Wr_w,
                              const float* __restrict__ Wr_b,
                              float* __restrict__ cvec) {
  int gw = blockIdx.x * 4 + (threadIdx.x >> 6);
  int lane = threadIdx.x & 63;
  int b = gw >> 10;
  int h = gw & 1023;
  const float* a1 = ht + b * D_DIM;
  const float* w1 = Wt_w + (size_t)h * D_DIM;
  const float* a2 = hm + b * H_DIM;
  const float* w2 = Wr_w + (size_t)h * H_DIM;
  float acc = 0.f;
#pragma unroll
  for (int i = 0; i < 4; ++i) {
    int d = lane * 4 + i * 256;
    float4 x1 = *(const float4*)(a1 + d);
    float4 y1 = *(const float4*)(w1 + d);
    float4 x2 = *(const float4*)(a2 + d);
    float4 y2 = *(const float4*)(w2 + d);
    acc += x1.x * y1.x + x1.y * y1.y + x1.z * y1.z + x1.w * y1.w;
    acc += x2.x * y2.x + x2.y * y2.y + x2.z * y2.z + x2.w * y2.w;
  }
#pragma unroll
  for (int off = 32; off >= 1; off >>= 1) acc += __shfl_xor(acc, off);
  if (lane == 0) cvec[b * H_DIM + h] = acc + Wt_b[h] + Wr_b[h];
}

// ---------- m97-exact 128x128 fused GEMM (round-11 verified, 179 us) -------
// BK=64, single-buffer 33 KB LDS, 4 blocks/CU, 2 barriers/K-step, 32 MFMA
// between barrier pairs. Epilogue: atomicAdd partial row-scores into the
// single score[] buffer (8 adds/element across nc) -> softmax reads NP=1.
__global__ __launch_bounds__(256, 4) void score_gemm9_kernel(
    const unsigned short* __restrict__ hsb,
    const unsigned short* __restrict__ Wsb,
    const float* __restrict__ cvec,
    const float* __restrict__ We_w,
    float* __restrict__ score) {
  __shared__ __align__(16) unsigned short lA[8192];  // 128 x 64 bf16 = 16 KB
  __shared__ __align__(16) unsigned short lB[8192];
  __shared__ float scorebuf[2][128];

  const int tid = threadIdx.x;
  const int lane = tid & 63;
  const int wave = tid >> 6;
  const int wr = wave >> 1;  // 0..1 : 64-row half
  const int wc = wave & 1;   // 0..1 : 64-col half
  const int l15 = lane & 15;
  const int lg = lane >> 4;

  // XCD-chunked bijective swizzle (4096 % 8 == 0); nc-siblings contiguous
  int dd = blockIdx.x;
  int tileid = (dd & 7) * 512 + (dd >> 3);
  const int mtile = tileid >> 3;
  const int nc = tileid & 7;
  const int m0 = mtile * 128;
  const int n0 = nc * 128;
  const int b = m0 >> 12;

  // staging: thread t covers LDS elems {t*8 + i*2048, i=0..3} per operand
  //   -> row_i = (t>>3) + 32*i (row&7 invariant in i), phys slot = t&7
  const int r0 = tid >> 3;
  const int sl = tid & 7;
  const int c0 = ((sl ^ (r0 & 7)) << 3);  // pre-swizzled source col
  const unsigned short* pA = hsb + (size_t)(m0 + r0) * D_DIM + c0;
  const unsigned short* pB = Wsb + (size_t)(n0 + r0) * D_DIM + c0;
  const int dst = tid * 8;

  // fragment bases: row&7 == l15&7 for all mi/ni (16-row steps)
  const int arow = wr * 64 + l15;
  const int brow = wc * 64 + l15;
  const int swz0 = ((lg ^ (l15 & 7)) << 3);        // kk=0 slots 0..3
  const int swz1 = (((4 + lg) ^ (l15 & 7)) << 3);  // kk=1 slots 4..7
  const int aoff0 = arow * 64 + swz0;
  const int aoff1 = arow * 64 + swz1;
  const int boff0 = brow * 64 + swz0;
  const int boff1 = brow * 64 + swz1;

  f32x4 acc[4][4];
#pragma unroll
  for (int i = 0; i < 4; ++i)
#pragma unroll
    for (int j = 0; j < 4; ++j) acc[i][j] = (f32x4){0.f, 0.f, 0.f, 0.f};

#pragma unroll
  for (int s = 0; s < 16; ++s) {
    const int KO = s * 64;  // compile-time literal after full unroll
#pragma unroll
    for (int i = 0; i < 4; ++i)
      gload_lds16(&lA[dst + i * 2048], pA + (size_t)i * 32768 + KO);
#pragma unroll
    for (int i = 0; i < 4; ++i)
      gload_lds16(&lB[dst + i * 2048], pB + (size_t)i * 32768 + KO);
    __syncthreads();  // vmcnt drain: slab landed
    short8 fa[4], fb[4];
    // kk = 0
#pragma unroll
    for (int ni = 0; ni < 4; ++ni)
      fb[ni] = *(const short8*)(lB + boff0 + ni * 1024);
#pragma unroll
    for (int mi = 0; mi < 4; ++mi)
      fa[mi] = *(const short8*)(lA + aoff0 + mi * 1024);
#pragma unroll
    for (int mi = 0; mi < 4; ++mi)
#pragma unroll
      for (int ni = 0; ni < 4; ++ni)
        acc[mi][ni] = __builtin_amdgcn_mfma_f32_16x16x32_bf16(
            fa[mi], fb[ni], acc[mi][ni], 0, 0, 0);
    // kk = 1
#pragma unroll
    for (int ni = 0; ni < 4; ++ni)
      fb[ni] = *(const short8*)(lB + boff1 + ni * 1024);
#pragma unroll
    for (int mi = 0; mi < 4; ++mi)
      fa[mi] = *(const short8*)(lA + aoff1 + mi * 1024);
#pragma unroll
    for (int mi = 0; mi < 4; ++mi)
#pragma unroll
      for (int ni = 0; ni < 4; ++ni)
        acc[mi][ni] = __builtin_amdgcn_mfma_f32_16x16x32_bf16(
            fa[mi], fb[ni], acc[mi][ni], 0, 0, 0);
    __syncthreads();  // reads done: safe to overwrite buffer next step
  }

  // epilogue: tanh(acc + c)*We, reduce over this block's 128 columns
  float chv[4], whv[4];
#pragma unroll
  for (int ni = 0; ni < 4; ++ni) {
    int h = n0 + wc * 64 + ni * 16 + l15;
    chv[ni] = cvec[b * H_DIM + h];
    whv[ni] = We_w[h];
  }
#pragma unroll
  for (int mi = 0; mi < 4; ++mi)
#pragma unroll
    for (int r = 0; r < 4; ++r) {
      float s = 0.f;
#pragma unroll
      for (int ni = 0; ni < 4; ++ni)
        s += tanh_fast(acc[mi][ni][r] + chv[ni]) * whv[ni];
      s += __shfl_xor(s, 1);
      s += __shfl_xor(s, 2);
      s += __shfl_xor(s, 4);
      s += __shfl_xor(s, 8);
      if (l15 == 0) scorebuf[wc][wr * 64 + mi * 16 + lg * 4 + r] = s;
    }
  __syncthreads();
  if (tid < 128) {
    atomicAdd(&score[m0 + tid], scorebuf[0][tid] + scorebuf[1][tid]);
  }
}

// ---------- fallback GEMM (round-1 structure, fp32 A in-kernel cvt) ----------
__global__ __launch_bounds__(256) void score_gemm_fp32_kernel(
    const float* __restrict__ hs,
    const unsigned short* __restrict__ Wsb,
    const float* __restrict__ cvec,
    const float* __restrict__ We_w,
    float* __restrict__ score_part) {
  __shared__ __align__(16) unsigned short lA[128 * 64];
  __shared__ __align__(16) unsigned short lB[128 * 64];
  __shared__ float scorebuf[2][128];

  const int tid = threadIdx.x;
  const int lane = tid & 63;
  const int wave = tid >> 6;
  const int wr = wave >> 1;
  const int wc = wave & 1;
  const int mtile = blockIdx.x;
  const int gy = blockIdx.y;
  const int m0 = mtile * 128;
  const int b = mtile >> 5;
  const int l15 = lane & 15;
  const int lg = lane >> 4;

  float rowsum[4][4];
#pragma unroll
  for (int i = 0; i < 4; ++i)
#pragma unroll
    for (int j = 0; j < 4; ++j) rowsum[i][j] = 0.f;

  for (int ncq = gy * 4; ncq < gy * 4 + 4; ++ncq) {
    const int n0 = ncq * 128;
    f32x4 acc[4][4];
#pragma unroll
    for (int i = 0; i < 4; ++i)
#pragma unroll
      for (int j = 0; j < 4; ++j) acc[i][j] = (f32x4){0.f, 0.f, 0.f, 0.f};

    for (int k0 = 0; k0 < D_DIM; k0 += 64) {
#pragma unroll
      for (int r = 0; r < 4; ++r) {
        int s = tid + r * 256;
        int row = s >> 3, slx = s & 7;
        int src = slx ^ (row & 7);
        gload_lds16(&lB[s * 8], Wsb + (size_t)(n0 + row) * D_DIM + k0 + src * 8);
      }
      float4 a0[4], a1[4];
#pragma unroll
      for (int r = 0; r < 4; ++r) {
        int s = tid + r * 256;
        int row = s >> 3, slx = s & 7;
        int src = slx ^ (row & 7);
        const float* ga = hs + (size_t)(m0 + row) * D_DIM + k0 + src * 8;
        a0[r] = *(const float4*)ga;
        a1[r] = *(const float4*)(ga + 4);
      }
#pragma unroll
      for (int r = 0; r < 4; ++r) {
        int s = tid + r * 256;
        union { unsigned short us[8]; short8 v; } pk;
        pk.us[0] = f2bf(a0[r].x); pk.us[1] = f2bf(a0[r].y);
        pk.us[2] = f2bf(a0[r].z); pk.us[3] = f2bf(a0[r].w);
        pk.us[4] = f2bf(a1[r].x); pk.us[5] = f2bf(a1[r].y);
        pk.us[6] = f2bf(a1[r].z); pk.us[7] = f2bf(a1[r].w);
        *(short8*)(&lA[s * 8]) = pk.v;
      }
      __syncthreads();
#pragma unroll
      for (int kf = 0; kf < 2; ++kf) {
        short8 af[4], bfr[4];
        int cgrp = kf * 4 + lg;
#pragma unroll
        for (int mi = 0; mi < 4; ++mi) {
          int row = wr * 64 + mi * 16 + l15;
          af[mi] = *(const short8*)&lA[row * 64 + (cgrp ^ (row & 7)) * 8];
        }
#pragma unroll
        for (int ni = 0; ni < 4; ++ni) {
          int row = wc * 64 + ni * 16 + l15;
          bfr[ni] = *(const short8*)&lB[row * 64 + (cgrp ^ (row & 7)) * 8];
        }
#pragma unroll
        for (int mi = 0; mi < 4; ++mi)
#pragma unroll
          for (int ni = 0; ni < 4; ++ni)
            acc[mi][ni] = __builtin_amdgcn_mfma_f32_16x16x32_bf16(
                af[mi], bfr[ni], acc[mi][ni], 0, 0, 0);
      }
      __syncthreads();
    }
#pragma unroll
    for (int ni = 0; ni < 4; ++ni) {
      int h = n0 + wc * 64 + ni * 16 + l15;
      float ch = cvec[b * H_DIM + h];
      float wh = We_w[h];
#pragma unroll
      for (int mi = 0; mi < 4; ++mi)
#pragma unroll
        for (int r2 = 0; r2 < 4; ++r2)
          rowsum[mi][r2] += tanh_fast(acc[mi][ni][r2] + ch) * wh;
    }
  }
#pragma unroll
  for (int mi = 0; mi < 4; ++mi)
#pragma unroll
    for (int r2 = 0; r2 < 4; ++r2) {
      float v = rowsum[mi][r2];
      v += __shfl_xor(v, 1);
      v += __shfl_xor(v, 2);
      v += __shfl_xor(v, 4);
      v += __shfl_xor(v, 8);
      rowsum[mi][r2] = v;
    }
  if (l15 == 0) {
#pragma unroll
    for (int mi = 0; mi < 4; ++mi)
#pragma unroll
      for (int r2 = 0; r2 < 4; ++r2)
        scorebuf[wc][wr * 64 + mi * 16 + lg * 4 + r2] = rowsum[mi][r2];
  }
  __syncthreads();
  if (tid < 128) {
    score_part[(size_t)gy * M_TOT + m0 + tid] =
        scorebuf[0][tid] + scorebuf[1][tid];
  }
}

// ---------- softmax (single combined score buffer), 1024 thr/block ---------
__global__ __launch_bounds__(1024) void softmax1_kernel(
    const float* __restrict__ score,
    const int* __restrict__ hs_i,
    const int* __restrict__ ht_i,
    const float* __restrict__ emb,
    const float* __restrict__ lam,
    float* __restrict__ wout) {
  int b = blockIdx.x;
  int tid = threadIdx.x;
  int wave = tid >> 6;
  int lane = tid & 63;
  float lam0 = lam[0], lam1 = lam[1], lam2 = lam[2];
  int tk = ht_i[b];
  float xs[4];
  float mx = -1e30f;
#pragma unroll
  for (int i = 0; i < 4; ++i) {
    int s = tid + i * 1024;
    size_t m = (size_t)b * S_LEN + s;
    float x = score[m];
    int idx = hs_i[m] * 512 + tk;
    const float* e = emb + (size_t)idx * 3;
    x += e[0] * lam0 + e[1] * lam1 + e[2] * lam2;
    xs[i] = x;
    mx = fmaxf(mx, x);
  }
  __shared__ float redm[16];
  __shared__ float reds[16];
#pragma unroll
  for (int off = 32; off >= 1; off >>= 1) mx = fmaxf(mx, __shfl_xor(mx, off));
  if (lane == 0) redm[wave] = mx;
  __syncthreads();
  mx = redm[0];
#pragma unroll
  for (int w = 1; w < 16; ++w) mx = fmaxf(mx, redm[w]);
  float sum = 0.f;
#pragma unroll
  for (int i = 0; i < 4; ++i) {
    xs[i] = __expf(xs[i] - mx);
    sum += xs[i];
  }
#pragma unroll
  for (int off = 32; off >= 1; off >>= 1) sum += __shfl_xor(sum, off);
  if (lane == 0) reds[wave] = sum;
  __syncthreads();
  sum = 0.f;
#pragma unroll
  for (int w = 0; w < 16; ++w) sum += reds[w];
  float inv = 1.0f / sum;
#pragma unroll
  for (int i = 0; i < 4; ++i)
    wout[(size_t)b * S_LEN + tid + i * 1024] = xs[i] * inv;
}

// ---------- softmax for fallback path (NP partials) ----------
template <int NP>
__global__ void softmax_kernel(const float* __restrict__ part,
                               const int* __restrict__ hs_i,
                               const int* __restrict__ ht_i,
                               const float* __restrict__ emb,
                               const float* __restrict__ lam,
                               float* __restrict__ wout) {
  int b = blockIdx.x;
  int tid = threadIdx.x;
  float lam0 = lam[0], lam1 = lam[1], lam2 = lam[2];
  int tk = ht_i[b];
  float xs[16];
  float mx = -1e30f;
#pragma unroll
  for (int i = 0; i < 16; ++i) {
    int s = tid + i * 256;
    size_t m = (size_t)b * S_LEN + s;
    float x = 0.f;
#pragma unroll
    for (int g = 0; g < NP; ++g) x += part[(size_t)g * M_TOT + m];
    int idx = hs_i[m] * 512 + tk;
    const float* e = emb + (size_t)idx * 3;
    x += e[0] * lam0 + e[1] * lam1 + e[2] * lam2;
    xs[i] = x;
    mx = fmaxf(mx, x);
  }
  __shared__ float redm[4];
  __shared__ float reds[4];
#pragma unroll
  for (int off = 32; off >= 1; off >>= 1) mx = fmaxf(mx, __shfl_xor(mx, off));
  if ((tid & 63) == 0) redm[tid >> 6] = mx;
  __syncthreads();
  mx = fmaxf(fmaxf(redm[0], redm[1]), fmaxf(redm[2], redm[3]));
  float sum = 0.f;
#pragma unroll
  for (int i = 0; i < 16; ++i) {
    xs[i] = __expf(xs[i] - mx);
    sum += xs[i];
  }
#pragma unroll
  for (int off = 32; off >= 1; off >>= 1) sum += __shfl_xor(sum, off);
  if ((tid & 63) == 0) reds[tid >> 6] = sum;
  __syncthreads();
  sum = reds[0] + reds[1] + reds[2] + reds[3];
  float inv = 1.0f / sum;
#pragma unroll
  for (int i = 0; i < 16; ++i)
    wout[(size_t)b * S_LEN + tid + i * 256] = xs[i] * inv;
}

// ---------- wsum (bf16 input) ----------
__global__ void wsum_bf16_kernel(const unsigned short* __restrict__ hsb,
                                 const float* __restrict__ w,
                                 float* __restrict__ u) {
  int bx = blockIdx.x;
  int b = bx >> 5;
  int sc = bx & 31;
  int tid = threadIdx.x;
  int dcol = tid * 4;
  int s0 = sc * 128;
  const unsigned short* base = hsb + ((size_t)b * S_LEN + s0) * D_DIM + dcol;
  const float* wrow = w + (size_t)b * S_LEN + s0;
  float4 acc = {0.f, 0.f, 0.f, 0.f};
#pragma unroll 4
  for (int i = 0; i < 128; ++i) {
    float ww = wrow[i];
    ushort2 v01 = *(const ushort2*)(base + (size_t)i * D_DIM);
    ushort2 v23 = *(const ushort2*)(base + (size_t)i * D_DIM + 2);
    acc.x += ww * __uint_as_float((unsigned int)v01.x << 16);
    acc.y += ww * __uint_as_float((unsigned int)v01.y << 16);
    acc.z += ww * __uint_as_float((unsigned int)v23.x << 16);
    acc.w += ww * __uint_as_float((unsigned int)v23.y << 16);
  }
  atomicAdd(&u[b * D_DIM + dcol + 0], acc.x);
  atomicAdd(&u[b * D_DIM + dcol + 1], acc.y);
  atomicAdd(&u[b * D_DIM + dcol + 2], acc.z);
  atomicAdd(&u[b * D_DIM + dcol + 3], acc.w);
}

// ---------- wsum (fp32 fallback) ----------
__global__ void wsum_kernel(const float* __restrict__ hs,
                            const float* __restrict__ w,
                            float* __restrict__ u) {
  int bx = blockIdx.x;
  int b = bx >> 5;
  int sc = bx & 31;
  int tid = threadIdx.x;
  int dcol = tid * 4;
  int s0 = sc * 128;
  const float* base = hs + ((size_t)b * S_LEN + s0) * D_DIM + dcol;
  const float* wrow = w + (size_t)b * S_LEN + s0;
  float4 acc = {0.f, 0.f, 0.f, 0.f};
#pragma unroll 4
  for (int i = 0; i < 128; ++i) {
    float ww = wrow[i];
    float4 v = *(const float4*)(base + (size_t)i * D_DIM);
    acc.x += ww * v.x;
    acc.y += ww * v.y;
    acc.z += ww * v.z;
    acc.w += ww * v.w;
  }
  atomicAdd(&u[b * D_DIM + dcol + 0], acc.x);
  atomicAdd(&u[b * D_DIM + dcol + 1], acc.y);
  atomicAdd(&u[b * D_DIM + dcol + 2], acc.z);
  atomicAdd(&u[b * D_DIM + dcol + 3], acc.w);
}

// ---------- alpha[b,h] = u[b]·Ws_w[h] + Ws_b[h] ----------
__global__ void alpha_kernel(const float* __restrict__ u,
                             const float* __restrict__ Ws_w,
                             const float* __restrict__ Ws_b,
                             float* __restrict__ out) {
  int gw = blockIdx.x * 4 + (threadIdx.x >> 6);
  int lane = threadIdx.x & 63;
  int b = gw >> 10;
  int h = gw & 1023;
  const float* ur = u + b * D_DIM;
  const float* wrow = Ws_w + (size_t)h * D_DIM;
  float acc = 0.f;
#pragma unroll
  for (int i = 0; i < 4; ++i) {
    int dcol = lane * 4 + i * 256;
    float4 x = *(const float4*)(ur + dcol);
    float4 y = *(const float4*)(wrow + dcol);
    acc += x.x * y.x + x.y * y.y + x.z * y.z + x.w * y.w;
  }
#pragma unroll
  for (int off = 32; off >= 1; off >>= 1) acc += __shfl_xor(acc, off);
  if (lane == 0) out[b * H_DIM + h] = acc + Ws_b[h];
}

extern "C" void kernel_launch(void* const* d_in, const int* in_sizes, int n_in,
                              void* d_out, int out_size, void* d_ws,
                              size_t ws_size, hipStream_t stream) {
  const float* hs = (const float*)d_in[0];
  const float* ht_k = (const float*)d_in[1];
  const float* hm_k = (const float*)d_in[2];
  const float* Ws_w = (const float*)d_in[3];
  const float* Ws_b = (const float*)d_in[4];
  const float* Wt_w = (const float*)d_in[5];
  const float* Wt_b = (const float*)d_in[6];
  const float* Wr_w = (const float*)d_in[7];
  const float* Wr_b = (const float*)d_in[8];
  const float* We_w = (const float*)d_in[9];
  const float* emb = (const float*)d_in[11];
  const float* lam = (const float*)d_in[12];
  const int* hs_i = (const int*)d_in[13];
  const int* ht_i = (const int*)d_in[14];
  float* out = (float*)d_out;

  const size_t HSB = (size_t)M_TOT * D_DIM * 2;  // 128 MB
  // fast layout: [hsb][Wsb 2M][score 256K][wgt 256K][u 64K][cvec 64K]
  const size_t FAST_NEEDED =
      HSB + 2097152 + 262144 + 262144 + 65536 + 65536;

  char* ws = (char*)d_ws;
  if (ws_size >= FAST_NEEDED) {
    unsigned short* hsb = (unsigned short*)ws;
    unsigned short* Wsb = (unsigned short*)(ws + HSB);
    float* score = (float*)(ws + HSB + 2097152);
    float* wgt = (float*)(ws + HSB + 2097152 + 262144);
    float* u = (float*)(ws + HSB + 2097152 + 262144 + 262144);
    float* cvec = (float*)(ws + HSB + 2097152 + 262144 + 262144 + 65536);

    cvt_hs_kernel<<<32768, 256, 0, stream>>>(hs, hsb);
    cvt_w_kernel<<<512, 256, 0, stream>>>(Ws_w, Wsb);
    prep_c_kernel<<<4096, 256, 0, stream>>>(ht_k, hm_k, Wt_w, Wt_b, Wr_w,
                                            Wr_b, cvec);
    hipMemsetAsync(score, 0, M_TOT * sizeof(float), stream);
    score_gemm9_kernel<<<4096, 256, 0, stream>>>(hsb, Wsb, cvec, We_w, score);
    softmax1_kernel<<<16, 1024, 0, stream>>>(score, hs_i, ht_i, emb, lam,
                                             wgt);
    hipMemsetAsync(u, 0, B_SZ * D_DIM * sizeof(float), stream);
    wsum_bf16_kernel<<<512, 256, 0, stream>>>(hsb, wgt, u);
    alpha_kernel<<<4096, 256, 0, stream>>>(u, Ws_w, Ws_b, out);
    return;
  }

  // fallback: small-ws path
  unsigned short* Wsb = (unsigned short*)(ws);
  float* cvec = (float*)(ws + 2097152);
  float* part = (float*)(ws + 2097152 + 65536);
  float* wgt = (float*)(ws + 2097152 + 65536 + 524288);
  float* u = (float*)(ws + 2097152 + 65536 + 524288 + 262144);

  cvt_w_kernel<<<512, 256, 0, stream>>>(Ws_w, Wsb);
  prep_c_kernel<<<4096, 256, 0, stream>>>(ht_k, hm_k, Wt_w, Wt_b, Wr_w, Wr_b,
                                          cvec);
  dim3 g2(512, 2);
  score_gemm_fp32_kernel<<<g2, 256, 0, stream>>>(hs, Wsb, cvec, We_w, part);
  softmax_kernel<2><<<16, 256, 0, stream>>>(part, hs_i, ht_i, emb, lam, wgt);
  hipMemsetAsync(u, 0, B_SZ * D_DIM * sizeof(float), stream);
  wsum_kernel<<<512, 256, 0, stream>>>(hs, wgt, u);
  alpha_kernel<<<4096, 256, 0, stream>>>(u, Ws_w, Ws_b, out);
}

// Round 14
// 271.527 us; speedup vs baseline: 1.0502x; 1.0502x over previous
//
#include <hip/hip_runtime.h>
#include <hip/hip_bf16.h>
#include <cstdint>
#include <cstddef>

typedef __attribute__((ext_vector_type(4))) float f32x4;
typedef __attribute__((ext_vector_type(8))) short short8;

#define S_LEN 4096
#define D_DIM 1024
#define H_DIM 1024
#define B_SZ  16
#define M_TOT (B_SZ * S_LEN)  // 65536

// ---------- helpers ----------
__device__ __forceinline__ unsigned short f2bf(float f) {
  unsigned int u = __float_as_uint(f);
  u += 0x7fffu + ((u >> 16) & 1u);
  return (unsigned short)(u >> 16);
}

__device__ __forceinline__ void gload_lds16(void* lds, const void* g) {
  __builtin_amdgcn_global_load_lds(
      (const __attribute__((address_space(1))) unsigned int*)g,
      (__attribute__((address_space(3))) unsigned int*)lds, 16, 0, 0);
}

__device__ __forceinline__ float tanh_fast(float x) {
  return 1.0f - 2.0f / (1.0f + __expf(2.0f * x));
}

// ---------- kernel 0: hs fp32 -> bf16 ----------
__global__ void cvt_hs_kernel(const float* __restrict__ w,
                              unsigned short* __restrict__ o) {
  size_t i = ((size_t)blockIdx.x * 256 + threadIdx.x) * 8;
  float4 v0 = *(const float4*)(w + i);
  float4 v1 = *(const float4*)(w + i + 4);
  union { unsigned short us[8]; short8 v; } pk;
  pk.us[0] = f2bf(v0.x); pk.us[1] = f2bf(v0.y);
  pk.us[2] = f2bf(v0.z); pk.us[3] = f2bf(v0.w);
  pk.us[4] = f2bf(v1.x); pk.us[5] = f2bf(v1.y);
  pk.us[6] = f2bf(v1.z); pk.us[7] = f2bf(v1.w);
  *(short8*)(o + i) = pk.v;
}

// ---------- kernel 1: Ws_w fp32 -> bf16 ----------
__global__ void cvt_w_kernel(const float* __restrict__ w,
                             unsigned short* __restrict__ o) {
  int i = (blockIdx.x * 256 + threadIdx.x) * 8;
  float4 v0 = *(const float4*)(w + i);
  float4 v1 = *(const float4*)(w + i + 4);
  union { unsigned short us[8]; short8 v; } pk;
  pk.us[0] = f2bf(v0.x); pk.us[1] = f2bf(v0.y);
  pk.us[2] = f2bf(v0.z); pk.us[3] = f2bf(v0.w);
  pk.us[4] = f2bf(v1.x); pk.us[5] = f2bf(v1.y);
  pk.us[6] = f2bf(v1.z); pk.us[7] = f2bf(v1.w);
  *(short8*)(o + i) = pk.v;
}

// ---------- kernel 2: c[b,h] ----------
__global__ void prep_c_kernel(const float* __restrict__ ht,
                              const float* __restrict__ hm,
                              const float* __restrict__ Wt_w,
                              const float* __restrict__ Wt_b,
                              const float* __restrict__ Wr_w,
                              const float* __restrict__ Wr_b,
                              float* __restrict__ cvec) {
  int gw = blockIdx.x * 4 + (threadIdx.x >> 6);
  int lane = threadIdx.x & 63;
  int b = gw >> 10;
  int h = gw & 1023;
  const float* a1 = ht + b * D_DIM;
  const float* w1 = Wt_w + (size_t)h * D_DIM;
  const float* a2 = hm + b * H_DIM;
  const float* w2 = Wr_w + (size_t)h * H_DIM;
  float acc = 0.f;
#pragma unroll
  for (int i = 0; i < 4; ++i) {
    int d = lane * 4 + i * 256;
    float4 x1 = *(const float4*)(a1 + d);
    float4 y1 = *(const float4*)(w1 + d);
    float4 x2 = *(const float4*)(a2 + d);
    float4 y2 = *(const float4*)(w2 + d);
    acc += x1.x * y1.x + x1.y * y1.y + x1.z * y1.z + x1.w * y1.w;
    acc += x2.x * y2.x + x2.y * y2.y + x2.z * y2.z + x2.w * y2.w;
  }
#pragma unroll
  for (int off = 32; off >= 1; off >>= 1) acc += __shfl_xor(acc, off);
  if (lane == 0) cvec[b * H_DIM + h] = acc + Wt_b[h] + Wr_b[h];
}

// ---------- 256x256 8-phase counted-vmcnt fused GEMM (r12 kernel; fastest
// by total-time arithmetic: replay ~165 us; profiled ~200 is a counter-
// collection artifact). Epilogue now atomicAdds into the single score[]
// buffer (4 contributions per element across nc). ----------
__global__ __launch_bounds__(512, 2) void score_gemm10_kernel(
    const unsigned short* __restrict__ hsb,
    const unsigned short* __restrict__ Wsb,
    const float* __restrict__ cvec,
    const float* __restrict__ We_w,
    float* __restrict__ score) {
  extern __shared__ unsigned short dynls[];
  unsigned short* lA = dynls;            // [2][16384]: par*16384 + half*8192
  unsigned short* lB = dynls + 32768;
  __shared__ float scorebuf[4][256];

  const int tid = threadIdx.x;
  const int lane = tid & 63;
  const int wave = tid >> 6;
  const int wm = wave >> 2;  // 0..1 : 128-row half
  const int wn = wave & 3;   // 0..3 : 64-col slice
  const int l15 = lane & 15;
  const int lg = lane >> 4;

  // XCD-chunked bijective swizzle (1024 % 8 == 0)
  int dd = blockIdx.x;
  int tileid = (dd & 7) * 128 + (dd >> 3);
  const int mtile = tileid >> 2;
  const int nc = tileid & 3;
  const int m0 = mtile * 256;
  const int n0 = nc * 256;
  const int b = m0 >> 12;

  // staging: per half-tile thread covers rows (tid>>3) and 64+(tid>>3),
  // phys slot tid&7; source col pre-swizzled (both-sides rule)
  const int r0 = tid >> 3;
  const int sl = tid & 7;
  const int c0 = ((sl ^ (r0 & 7)) << 3);
  const unsigned short* pA = hsb + (size_t)(m0 + r0) * D_DIM + c0;
  const unsigned short* pB = Wsb + (size_t)(n0 + r0) * D_DIM + c0;
  const int dst0 = tid * 8;
  const int dst1 = 4096 + tid * 8;

#define STG_A0(T)                                                     \
  do {                                                                \
    gload_lds16(lA + ((T)&1) * 16384 + dst0, pA + (T) * 64);          \
    gload_lds16(lA + ((T)&1) * 16384 + dst1, pA + 65536 + (T) * 64);  \
  } while (0)
#define STG_A1(T)                                                     \
  do {                                                                \
    gload_lds16(lA + ((T)&1) * 16384 + 8192 + dst0,                   \
                pA + 131072 + (T) * 64);                              \
    gload_lds16(lA + ((T)&1) * 16384 + 8192 + dst1,                   \
                pA + 131072 + 65536 + (T) * 64);                      \
  } while (0)
#define STG_B0(T)                                                     \
  do {                                                                \
    gload_lds16(lB + ((T)&1) * 16384 + dst0, pB + (T) * 64);          \
    gload_lds16(lB + ((T)&1) * 16384 + dst1, pB + 65536 + (T) * 64);  \
  } while (0)
#define STG_B1(T)                                                     \
  do {                                                                \
    gload_lds16(lB + ((T)&1) * 16384 + 8192 + dst0,                   \
                pB + 131072 + (T) * 64);                              \
    gload_lds16(lB + ((T)&1) * 16384 + 8192 + dst1,                   \
                pB + 131072 + 65536 + (T) * 64);                      \
  } while (0)

  // fragment bases (elements); XOR slot invariant across mi/ni (16-row steps)
  const int swz0 = ((lg ^ (l15 & 7)) << 3);        // kk=0
  const int swz1 = (((4 + lg) ^ (l15 & 7)) << 3);  // kk=1
  const int afix = wm * 8192 + l15 * 64;
  const int bfix = (wn >> 1) * 8192 + ((wn & 1) * 64 + l15) * 64;

  f32x4 acc[8][4];
#pragma unroll
  for (int i = 0; i < 8; ++i)
#pragma unroll
    for (int j = 0; j < 4; ++j) acc[i][j] = (f32x4){0.f, 0.f, 0.f, 0.f};

#define BAR() __builtin_amdgcn_s_barrier()
#define VM(N) asm volatile("s_waitcnt vmcnt(" #N ")" ::: "memory")

#define MM16(ACB, FA, FB)                                                  \
  {                                                                        \
    __builtin_amdgcn_s_setprio(1);                                         \
    _Pragma("unroll") for (int kk = 0; kk < 2; ++kk) {                     \
      _Pragma("unroll") for (int mi = 0; mi < 4; ++mi) {                   \
        _Pragma("unroll") for (int ni = 0; ni < 2; ++ni) {                 \
          ACB = __builtin_amdgcn_mfma_f32_16x16x32_bf16(                   \
              FA[kk * 4 + mi], FB[kk * 2 + ni], ACB, 0, 0, 0);             \
        }                                                                  \
      }                                                                    \
    }                                                                      \
    __builtin_amdgcn_s_setprio(0);                                         \
  }

#define TILE(T, S0, S1, S2, S3, WQ)                                        \
  {                                                                        \
    short8 fa_lo[8], fa_hi[8], fb_lo[4], fb_hi[4];                         \
    /* p0 */                                                               \
    _Pragma("unroll") for (int kk = 0; kk < 2; ++kk) {                     \
      const int sw = kk ? swz1 : swz0;                                     \
      _Pragma("unroll") for (int mi = 0; mi < 4; ++mi)                     \
          fa_lo[kk * 4 + mi] = *(const short8*)(lA + ((T)&1) * 16384 +     \
                                                afix + mi * 1024 + sw);    \
      _Pragma("unroll") for (int ni = 0; ni < 2; ++ni)                     \
          fb_lo[kk * 2 + ni] = *(const short8*)(lB + ((T)&1) * 16384 +     \
                                                bfix + ni * 1024 + sw);    \
    }                                                                      \
    S0;                                                                    \
    BAR();                                                                 \
    MM16(acc[mi][ni], fa_lo, fb_lo);                                       \
    BAR();                                                                 \
    /* p1 */                                                               \
    _Pragma("unroll") for (int kk = 0; kk < 2; ++kk) {                     \
      const int sw = kk ? swz1 : swz0;                                     \
      _Pragma("unroll") for (int mi = 0; mi < 4; ++mi)                     \
          fa_hi[kk * 4 + mi] = *(const short8*)(lA + ((T)&1) * 16384 +     \
                                                afix + 4096 + mi * 1024 +  \
                                                sw);                       \
    }                                                                      \
    S1;                                                                    \
    BAR();                                                                 \
    MM16(acc[4 + mi][ni], fa_hi, fb_lo);                                   \
    BAR();                                                                 \
    /* p2 */                                                               \
    _Pragma("unroll") for (int kk = 0; kk < 2; ++kk) {                     \
      const int sw = kk ? swz1 : swz0;                                     \
      _Pragma("unroll") for (int ni = 0; ni < 2; ++ni)                     \
          fb_hi[kk * 2 + ni] = *(const short8*)(lB + ((T)&1) * 16384 +     \
                                                bfix + 2048 + ni * 1024 +  \
                                                sw);                       \
    }                                                                      \
    S2;                                                                    \
    BAR();                                                                 \
    MM16(acc[4 + mi][2 + ni], fa_hi, fb_hi);                               \
    BAR();                                                                 \
    /* p3 */                                                               \
    S3;                                                                    \
    BAR();                                                                 \
    MM16(acc[mi][2 + ni], fa_lo, fb_hi);                                   \
    WQ;                                                                    \
    BAR();                                                                 \
  }

  // prologue: tile0 all 4 half-tiles + tile1 A0,A1; certify tile0
  STG_A0(0); STG_A1(0); STG_B0(0); STG_B1(0);
  STG_A0(1); STG_A1(1);
  VM(4);
  BAR();

  TILE(0, STG_B0(1), STG_B1(1), STG_A0(2), STG_A1(2), VM(4))
  TILE(1, STG_B0(2), STG_B1(2), STG_A0(3), STG_A1(3), VM(4))
  TILE(2, STG_B0(3), STG_B1(3), STG_A0(4), STG_A1(4), VM(4))
  TILE(3, STG_B0(4), STG_B1(4), STG_A0(5), STG_A1(5), VM(4))
  TILE(4, STG_B0(5), STG_B1(5), STG_A0(6), STG_A1(6), VM(4))
  TILE(5, STG_B0(6), STG_B1(6), STG_A0(7), STG_A1(7), VM(4))
  TILE(6, STG_B0(7), STG_B1(7), STG_A0(8), STG_A1(8), VM(4))
  TILE(7, STG_B0(8), STG_B1(8), STG_A0(9), STG_A1(9), VM(4))
  TILE(8, STG_B0(9), STG_B1(9), STG_A0(10), STG_A1(10), VM(4))
  TILE(9, STG_B0(10), STG_B1(10), STG_A0(11), STG_A1(11), VM(4))
  TILE(10, STG_B0(11), STG_B1(11), STG_A0(12), STG_A1(12), VM(4))
  TILE(11, STG_B0(12), STG_B1(12), STG_A0(13), STG_A1(13), VM(4))
  TILE(12, STG_B0(13), STG_B1(13), STG_A0(14), STG_A1(14), VM(4))
  TILE(13, STG_B0(14), STG_B1(14), STG_A0(15), STG_A1(15), VM(4))
  TILE(14, STG_B0(15), STG_B1(15), , , VM(0))
  TILE(15, , , , , )

#undef TILE
#undef MM16
#undef STG_A0
#undef STG_A1
#undef STG_B0
#undef STG_B1
#undef VM
#undef BAR

  // epilogue: tanh(acc + c)*We, reduce over this block's 256 columns
  float chv[4], whv[4];
#pragma unroll
  for (int ni = 0; ni < 4; ++ni) {
    int h = n0 + wn * 64 + ni * 16 + l15;
    chv[ni] = cvec[b * H_DIM + h];
    whv[ni] = We_w[h];
  }
#pragma unroll
  for (int mi = 0; mi < 8; ++mi)
#pragma unroll
    for (int r = 0; r < 4; ++r) {
      float s = 0.f;
#pragma unroll
      for (int ni = 0; ni < 4; ++ni)
        s += tanh_fast(acc[mi][ni][r] + chv[ni]) * whv[ni];
      s += __shfl_xor(s, 1);
      s += __shfl_xor(s, 2);
      s += __shfl_xor(s, 4);
      s += __shfl_xor(s, 8);
      if (l15 == 0) scorebuf[wn][wm * 128 + mi * 16 + lg * 4 + r] = s;
    }
  __syncthreads();
  if (tid < 256) {
    float s = scorebuf[0][tid] + scorebuf[1][tid] + scorebuf[2][tid] +
              scorebuf[3][tid];
    atomicAdd(&score[m0 + tid], s);
  }
}

// ---------- fallback GEMM (round-1 structure, fp32 A in-kernel cvt) ----------
__global__ __launch_bounds__(256) void score_gemm_fp32_kernel(
    const float* __restrict__ hs,
    const unsigned short* __restrict__ Wsb,
    const float* __restrict__ cvec,
    const float* __restrict__ We_w,
    float* __restrict__ score_part) {
  __shared__ __align__(16) unsigned short lA[128 * 64];
  __shared__ __align__(16) unsigned short lB[128 * 64];
  __shared__ float scorebuf[2][128];

  const int tid = threadIdx.x;
  const int lane = tid & 63;
  const int wave = tid >> 6;
  const int wr = wave >> 1;
  const int wc = wave & 1;
  const int mtile = blockIdx.x;
  const int gy = blockIdx.y;
  const int m0 = mtile * 128;
  const int b = mtile >> 5;
  const int l15 = lane & 15;
  const int lg = lane >> 4;

  float rowsum[4][4];
#pragma unroll
  for (int i = 0; i < 4; ++i)
#pragma unroll
    for (int j = 0; j < 4; ++j) rowsum[i][j] = 0.f;

  for (int ncq = gy * 4; ncq < gy * 4 + 4; ++ncq) {
    const int n0 = ncq * 128;
    f32x4 acc[4][4];
#pragma unroll
    for (int i = 0; i < 4; ++i)
#pragma unroll
      for (int j = 0; j < 4; ++j) acc[i][j] = (f32x4){0.f, 0.f, 0.f, 0.f};

    for (int k0 = 0; k0 < D_DIM; k0 += 64) {
#pragma unroll
      for (int r = 0; r < 4; ++r) {
        int s = tid + r * 256;
        int row = s >> 3, slx = s & 7;
        int src = slx ^ (row & 7);
        gload_lds16(&lB[s * 8], Wsb + (size_t)(n0 + row) * D_DIM + k0 + src * 8);
      }
      float4 a0[4], a1[4];
#pragma unroll
      for (int r = 0; r < 4; ++r) {
        int s = tid + r * 256;
        int row = s >> 3, slx = s & 7;
        int src = slx ^ (row & 7);
        const float* ga = hs + (size_t)(m0 + row) * D_DIM + k0 + src * 8;
        a0[r] = *(const float4*)ga;
        a1[r] = *(const float4*)(ga + 4);
      }
#pragma unroll
      for (int r = 0; r < 4; ++r) {
        int s = tid + r * 256;
        union { unsigned short us[8]; short8 v; } pk;
        pk.us[0] = f2bf(a0[r].x); pk.us[1] = f2bf(a0[r].y);
        pk.us[2] = f2bf(a0[r].z); pk.us[3] = f2bf(a0[r].w);
        pk.us[4] = f2bf(a1[r].x); pk.us[5] = f2bf(a1[r].y);
        pk.us[6] = f2bf(a1[r].z); pk.us[7] = f2bf(a1[r].w);
        *(short8*)(&lA[s * 8]) = pk.v;
      }
      __syncthreads();
#pragma unroll
      for (int kf = 0; kf < 2; ++kf) {
        short8 af[4], bfr[4];
        int cgrp = kf * 4 + lg;
#pragma unroll
        for (int mi = 0; mi < 4; ++mi) {
          int row = wr * 64 + mi * 16 + l15;
          af[mi] = *(const short8*)&lA[row * 64 + (cgrp ^ (row & 7)) * 8];
        }
#pragma unroll
        for (int ni = 0; ni < 4; ++ni) {
          int row = wc * 64 + ni * 16 + l15;
          bfr[ni] = *(const short8*)&lB[row * 64 + (cgrp ^ (row & 7)) * 8];
        }
#pragma unroll
        for (int mi = 0; mi < 4; ++mi)
#pragma unroll
          for (int ni = 0; ni < 4; ++ni)
            acc[mi][ni] = __builtin_amdgcn_mfma_f32_16x16x32_bf16(
                af[mi], bfr[ni], acc[mi][ni], 0, 0, 0);
      }
      __syncthreads();
    }
#pragma unroll
    for (int ni = 0; ni < 4; ++ni) {
      int h = n0 + wc * 64 + ni * 16 + l15;
      float ch = cvec[b * H_DIM + h];
      float wh = We_w[h];
#pragma unroll
      for (int mi = 0; mi < 4; ++mi)
#pragma unroll
        for (int r2 = 0; r2 < 4; ++r2)
          rowsum[mi][r2] += tanh_fast(acc[mi][ni][r2] + ch) * wh;
    }
  }
#pragma unroll
  for (int mi = 0; mi < 4; ++mi)
#pragma unroll
    for (int r2 = 0; r2 < 4; ++r2) {
      float v = rowsum[mi][r2];
      v += __shfl_xor(v, 1);
      v += __shfl_xor(v, 2);
      v += __shfl_xor(v, 4);
      v += __shfl_xor(v, 8);
      rowsum[mi][r2] = v;
    }
  if (l15 == 0) {
#pragma unroll
    for (int mi = 0; mi < 4; ++mi)
#pragma unroll
      for (int r2 = 0; r2 < 4; ++r2)
        scorebuf[wc][wr * 64 + mi * 16 + lg * 4 + r2] = rowsum[mi][r2];
  }
  __syncthreads();
  if (tid < 128) {
    score_part[(size_t)gy * M_TOT + m0 + tid] =
        scorebuf[0][tid] + scorebuf[1][tid];
  }
}

// ---------- softmax (single combined score buffer), 1024 thr/block ---------
__global__ __launch_bounds__(1024) void softmax1_kernel(
    const float* __restrict__ score,
    const int* __restrict__ hs_i,
    const int* __restrict__ ht_i,
    const float* __restrict__ emb,
    const float* __restrict__ lam,
    float* __restrict__ wout) {
  int b = blockIdx.x;
  int tid = threadIdx.x;
  int wave = tid >> 6;
  int lane = tid & 63;
  float lam0 = lam[0], lam1 = lam[1], lam2 = lam[2];
  int tk = ht_i[b];
  float xs[4];
  float mx = -1e30f;
#pragma unroll
  for (int i = 0; i < 4; ++i) {
    int s = tid + i * 1024;
    size_t m = (size_t)b * S_LEN + s;
    float x = score[m];
    int idx = hs_i[m] * 512 + tk;
    const float* e = emb + (size_t)idx * 3;
    x += e[0] * lam0 + e[1] * lam1 + e[2] * lam2;
    xs[i] = x;
    mx = fmaxf(mx, x);
  }
  __shared__ float redm[16];
  __shared__ float reds[16];
#pragma unroll
  for (int off = 32; off >= 1; off >>= 1) mx = fmaxf(mx, __shfl_xor(mx, off));
  if (lane == 0) redm[wave] = mx;
  __syncthreads();
  mx = redm[0];
#pragma unroll
  for (int w = 1; w < 16; ++w) mx = fmaxf(mx, redm[w]);
  float sum = 0.f;
#pragma unroll
  for (int i = 0; i < 4; ++i) {
    xs[i] = __expf(xs[i] - mx);
    sum += xs[i];
  }
#pragma unroll
  for (int off = 32; off >= 1; off >>= 1) sum += __shfl_xor(sum, off);
  if (lane == 0) reds[wave] = sum;
  __syncthreads();
  sum = 0.f;
#pragma unroll
  for (int w = 0; w < 16; ++w) sum += reds[w];
  float inv = 1.0f / sum;
#pragma unroll
  for (int i = 0; i < 4; ++i)
    wout[(size_t)b * S_LEN + tid + i * 1024] = xs[i] * inv;
}

// ---------- softmax for fallback path (NP partials) ----------
template <int NP>
__global__ void softmax_kernel(const float* __restrict__ part,
                               const int* __restrict__ hs_i,
                               const int* __restrict__ ht_i,
                               const float* __restrict__ emb,
                               const float* __restrict__ lam,
                               float* __restrict__ wout) {
  int b = blockIdx.x;
  int tid = threadIdx.x;
  float lam0 = lam[0], lam1 = lam[1], lam2 = lam[2];
  int tk = ht_i[b];
  float xs[16];
  float mx = -1e30f;
#pragma unroll
  for (int i = 0; i < 16; ++i) {
    int s = tid + i * 256;
    size_t m = (size_t)b * S_LEN + s;
    float x = 0.f;
#pragma unroll
    for (int g = 0; g < NP; ++g) x += part[(size_t)g * M_TOT + m];
    int idx = hs_i[m] * 512 + tk;
    const float* e = emb + (size_t)idx * 3;
    x += e[0] * lam0 + e[1] * lam1 + e[2] * lam2;
    xs[i] = x;
    mx = fmaxf(mx, x);
  }
  __shared__ float redm[4];
  __shared__ float reds[4];
#pragma unroll
  for (int off = 32; off >= 1; off >>= 1) mx = fmaxf(mx, __shfl_xor(mx, off));
  if ((tid & 63) == 0) redm[tid >> 6] = mx;
  __syncthreads();
  mx = fmaxf(fmaxf(redm[0], redm[1]), fmaxf(redm[2], redm[3]));
  float sum = 0.f;
#pragma unroll
  for (int i = 0; i < 16; ++i) {
    xs[i] = __expf(xs[i] - mx);
    sum += xs[i];
  }
#pragma unroll
  for (int off = 32; off >= 1; off >>= 1) sum += __shfl_xor(sum, off);
  if ((tid & 63) == 0) reds[tid >> 6] = sum;
  __syncthreads();
  sum = reds[0] + reds[1] + reds[2] + reds[3];
  float inv = 1.0f / sum;
#pragma unroll
  for (int i = 0; i < 16; ++i)
    wout[(size_t)b * S_LEN + tid + i * 256] = xs[i] * inv;
}

// ---------- wsum (bf16 input) ----------
__global__ void wsum_bf16_kernel(const unsigned short* __restrict__ hsb,
                                 const float* __restrict__ w,
                                 float* __restrict__ u) {
  int bx = blockIdx.x;
  int b = bx >> 5;
  int sc = bx & 31;
  int tid = threadIdx.x;
  int dcol = tid * 4;
  int s0 = sc * 128;
  const unsigned short* base = hsb + ((size_t)b * S_LEN + s0) * D_DIM + dcol;
  const float* wrow = w + (size_t)b * S_LEN + s0;
  float4 acc = {0.f, 0.f, 0.f, 0.f};
#pragma unroll 4
  for (int i = 0; i < 128; ++i) {
    float ww = wrow[i];
    ushort2 v01 = *(const ushort2*)(base + (size_t)i * D_DIM);
    ushort2 v23 = *(const ushort2*)(base + (size_t)i * D_DIM + 2);
    acc.x += ww * __uint_as_float((unsigned int)v01.x << 16);
    acc.y += ww * __uint_as_float((unsigned int)v01.y << 16);
    acc.z += ww * __uint_as_float((unsigned int)v23.x << 16);
    acc.w += ww * __uint_as_float((unsigned int)v23.y << 16);
  }
  atomicAdd(&u[b * D_DIM + dcol + 0], acc.x);
  atomicAdd(&u[b * D_DIM + dcol + 1], acc.y);
  atomicAdd(&u[b * D_DIM + dcol + 2], acc.z);
  atomicAdd(&u[b * D_DIM + dcol + 3], acc.w);
}

// ---------- wsum (fp32 fallback) ----------
__global__ void wsum_kernel(const float* __restrict__ hs,
                            const float* __restrict__ w,
                            float* __restrict__ u) {
  int bx = blockIdx.x;
  int b = bx >> 5;
  int sc = bx & 31;
  int tid = threadIdx.x;
  int dcol = tid * 4;
  int s0 = sc * 128;
  const float* base = hs + ((size_t)b * S_LEN + s0) * D_DIM + dcol;
  const float* wrow = w + (size_t)b * S_LEN + s0;
  float4 acc = {0.f, 0.f, 0.f, 0.f};
#pragma unroll 4
  for (int i = 0; i < 128; ++i) {
    float ww = wrow[i];
    float4 v = *(const float4*)(base + (size_t)i * D_DIM);
    acc.x += ww * v.x;
    acc.y += ww * v.y;
    acc.z += ww * v.z;
    acc.w += ww * v.w;
  }
  atomicAdd(&u[b * D_DIM + dcol + 0], acc.x);
  atomicAdd(&u[b * D_DIM + dcol + 1], acc.y);
  atomicAdd(&u[b * D_DIM + dcol + 2], acc.z);
  atomicAdd(&u[b * D_DIM + dcol + 3], acc.w);
}

// ---------- alpha[b,h] = u[b]·Ws_w[h] + Ws_b[h] ----------
__global__ void alpha_kernel(const float* __restrict__ u,
                             const float* __restrict__ Ws_w,
                             const float* __restrict__ Ws_b,
                             float* __restrict__ out) {
  int gw = blockIdx.x * 4 + (threadIdx.x >> 6);
  int lane = threadIdx.x & 63;
  int b = gw >> 10;
  int h = gw & 1023;
  const float* ur = u + b * D_DIM;
  const float* wrow = Ws_w + (size_t)h * D_DIM;
  float acc = 0.f;
#pragma unroll
  for (int i = 0; i < 4; ++i) {
    int dcol = lane * 4 + i * 256;
    float4 x = *(const float4*)(ur + dcol);
    float4 y = *(const float4*)(wrow + dcol);
    acc += x.x * y.x + x.y * y.y + x.z * y.z + x.w * y.w;
  }
#pragma unroll
  for (int off = 32; off >= 1; off >>= 1) acc += __shfl_xor(acc, off);
  if (lane == 0) out[b * H_DIM + h] = acc + Ws_b[h];
}

extern "C" void kernel_launch(void* const* d_in, const int* in_sizes, int n_in,
                              void* d_out, int out_size, void* d_ws,
                              size_t ws_size, hipStream_t stream) {
  const float* hs = (const float*)d_in[0];
  const float* ht_k = (const float*)d_in[1];
  const float* hm_k = (const float*)d_in[2];
  const float* Ws_w = (const float*)d_in[3];
  const float* Ws_b = (const float*)d_in[4];
  const float* Wt_w = (const float*)d_in[5];
  const float* Wt_b = (const float*)d_in[6];
  const float* Wr_w = (const float*)d_in[7];
  const float* Wr_b = (const float*)d_in[8];
  const float* We_w = (const float*)d_in[9];
  const float* emb = (const float*)d_in[11];
  const float* lam = (const float*)d_in[12];
  const int* hs_i = (const int*)d_in[13];
  const int* ht_i = (const int*)d_in[14];
  float* out = (float*)d_out;

  const size_t HSB = (size_t)M_TOT * D_DIM * 2;  // 128 MB
  // fast layout: [hsb][Wsb 2M][score 256K][wgt 256K][u 64K][cvec 64K]
  const size_t FAST_NEEDED =
      HSB + 2097152 + 262144 + 262144 + 65536 + 65536;

  char* ws = (char*)d_ws;
  if (ws_size >= FAST_NEEDED) {
    unsigned short* hsb = (unsigned short*)ws;
    unsigned short* Wsb = (unsigned short*)(ws + HSB);
    float* score = (float*)(ws + HSB + 2097152);
    float* wgt = (float*)(ws + HSB + 2097152 + 262144);
    float* u = (float*)(ws + HSB + 2097152 + 262144 + 262144);
    float* cvec = (float*)(ws + HSB + 2097152 + 262144 + 262144 + 65536);

    hipFuncSetAttribute((const void*)score_gemm10_kernel,
                        hipFuncAttributeMaxDynamicSharedMemorySize, 131072);

    cvt_hs_kernel<<<32768, 256, 0, stream>>>(hs, hsb);
    cvt_w_kernel<<<512, 256, 0, stream>>>(Ws_w, Wsb);
    prep_c_kernel<<<4096, 256, 0, stream>>>(ht_k, hm_k, Wt_w, Wt_b, Wr_w,
                                            Wr_b, cvec);
    hipMemsetAsync(score, 0, M_TOT * sizeof(float), stream);
    score_gemm10_kernel<<<1024, 512, 131072, stream>>>(hsb, Wsb, cvec, We_w,
                                                       score);
    softmax1_kernel<<<16, 1024, 0, stream>>>(score, hs_i, ht_i, emb, lam,
                                             wgt);
    hipMemsetAsync(u, 0, B_SZ * D_DIM * sizeof(float), stream);
    wsum_bf16_kernel<<<512, 256, 0, stream>>>(hsb, wgt, u);
    alpha_kernel<<<4096, 256, 0, stream>>>(u, Ws_w, Ws_b, out);
    return;
  }

  // fallback: small-ws path
  unsigned short* Wsb = (unsigned short*)(ws);
  float* cvec = (float*)(ws + 2097152);
  float* part = (float*)(ws + 2097152 + 65536);
  float* wgt = (float*)(ws + 2097152 + 65536 + 524288);
  float* u = (float*)(ws + 2097152 + 65536 + 524288 + 262144);

  cvt_w_kernel<<<512, 256, 0, stream>>>(Ws_w, Wsb);
  prep_c_kernel<<<4096, 256, 0, stream>>>(ht_k, hm_k, Wt_w, Wt_b, Wr_w, Wr_b,
                                          cvec);
  dim3 g2(512, 2);
  score_gemm_fp32_kernel<<<g2, 256, 0, stream>>>(hs, Wsb, cvec, We_w, part);
  softmax_kernel<2><<<16, 256, 0, stream>>>(part, hs_i, ht_i, emb, lam, wgt);
  hipMemsetAsync(u, 0, B_SZ * D_DIM * sizeof(float), stream);
  wsum_kernel<<<512, 256, 0, stream>>>(hs, wgt, u);
  alpha_kernel<<<4096, 256, 0, stream>>>(u, Ws_w, Ws_b, out);
}

// Round 15
// 264.588 us; speedup vs baseline: 1.0777x; 1.0262x over previous
//
#include <hip/hip_runtime.h>
#include <hip/hip_bf16.h>
#include <cstdint>
#include <cstddef>

typedef __attribute__((ext_vector_type(4))) float f32x4;
typedef __attribute__((ext_vector_type(8))) short short8;

#define S_LEN 4096
#define D_DIM 1024
#define H_DIM 1024
#define B_SZ  16
#define M_TOT (B_SZ * S_LEN)  // 65536

// ---------- helpers ----------
__device__ __forceinline__ unsigned short f2bf(float f) {
  unsigned int u = __float_as_uint(f);
  u += 0x7fffu + ((u >> 16) & 1u);
  return (unsigned short)(u >> 16);
}

__device__ __forceinline__ void gload_lds16(void* lds, const void* g) {
  __builtin_amdgcn_global_load_lds(
      (const __attribute__((address_space(1))) unsigned int*)g,
      (__attribute__((address_space(3))) unsigned int*)lds, 16, 0, 0);
}

__device__ __forceinline__ float tanh_fast(float x) {
  return 1.0f - 2.0f / (1.0f + __expf(2.0f * x));
}

// ---------- kernel 0: hs fp32 -> bf16 ----------
__global__ void cvt_hs_kernel(const float* __restrict__ w,
                              unsigned short* __restrict__ o) {
  size_t i = ((size_t)blockIdx.x * 256 + threadIdx.x) * 8;
  float4 v0 = *(const float4*)(w + i);
  float4 v1 = *(const float4*)(w + i + 4);
  union { unsigned short us[8]; short8 v; } pk;
  pk.us[0] = f2bf(v0.x); pk.us[1] = f2bf(v0.y);
  pk.us[2] = f2bf(v0.z); pk.us[3] = f2bf(v0.w);
  pk.us[4] = f2bf(v1.x); pk.us[5] = f2bf(v1.y);
  pk.us[6] = f2bf(v1.z); pk.us[7] = f2bf(v1.w);
  *(short8*)(o + i) = pk.v;
}

// ---------- fused weights prep: blocks [0,512) cvt Ws->bf16; rest cvec ----
__global__ void prep_fused_kernel(const float* __restrict__ Ws_w,
                                  unsigned short* __restrict__ Wsb,
                                  const float* __restrict__ ht,
                                  const float* __restrict__ hm,
                                  const float* __restrict__ Wt_w,
                                  const float* __restrict__ Wt_b,
                                  const float* __restrict__ Wr_w,
                                  const float* __restrict__ Wr_b,
                                  float* __restrict__ cvec) {
  if (blockIdx.x < 512) {
    int i = (blockIdx.x * 256 + threadIdx.x) * 8;
    float4 v0 = *(const float4*)(Ws_w + i);
    float4 v1 = *(const float4*)(Ws_w + i + 4);
    union { unsigned short us[8]; short8 v; } pk;
    pk.us[0] = f2bf(v0.x); pk.us[1] = f2bf(v0.y);
    pk.us[2] = f2bf(v0.z); pk.us[3] = f2bf(v0.w);
    pk.us[4] = f2bf(v1.x); pk.us[5] = f2bf(v1.y);
    pk.us[6] = f2bf(v1.z); pk.us[7] = f2bf(v1.w);
    *(short8*)(Wsb + i) = pk.v;
    return;
  }
  int gw = (blockIdx.x - 512) * 4 + (threadIdx.x >> 6);
  int lane = threadIdx.x & 63;
  int b = gw >> 10;
  int h = gw & 1023;
  const float* a1 = ht + b * D_DIM;
  const float* w1 = Wt_w + (size_t)h * D_DIM;
  const float* a2 = hm + b * H_DIM;
  const float* w2 = Wr_w + (size_t)h * H_DIM;
  float acc = 0.f;
#pragma unroll
  for (int i = 0; i < 4; ++i) {
    int d = lane * 4 + i * 256;
    float4 x1 = *(const float4*)(a1 + d);
    float4 y1 = *(const float4*)(w1 + d);
    float4 x2 = *(const float4*)(a2 + d);
    float4 y2 = *(const float4*)(w2 + d);
    acc += x1.x * y1.x + x1.y * y1.y + x1.z * y1.z + x1.w * y1.w;
    acc += x2.x * y2.x + x2.y * y2.y + x2.z * y2.z + x2.w * y2.w;
  }
#pragma unroll
  for (int off = 32; off >= 1; off >>= 1) acc += __shfl_xor(acc, off);
  if (lane == 0) cvec[b * H_DIM + h] = acc + Wt_b[h] + Wr_b[h];
}

// ---------- 256x256 8-phase counted-vmcnt fused GEMM (fastest by replay:
// ~165 us; profiled ~203 is a counter-collection artifact). Epilogue
// atomicAdds into the single score[] buffer. ----------
__global__ __launch_bounds__(512, 2) void score_gemm10_kernel(
    const unsigned short* __restrict__ hsb,
    const unsigned short* __restrict__ Wsb,
    const float* __restrict__ cvec,
    const float* __restrict__ We_w,
    float* __restrict__ score) {
  extern __shared__ unsigned short dynls[];
  unsigned short* lA = dynls;            // [2][16384]: par*16384 + half*8192
  unsigned short* lB = dynls + 32768;
  __shared__ float scorebuf[4][256];

  const int tid = threadIdx.x;
  const int lane = tid & 63;
  const int wave = tid >> 6;
  const int wm = wave >> 2;  // 0..1 : 128-row half
  const int wn = wave & 3;   // 0..3 : 64-col slice
  const int l15 = lane & 15;
  const int lg = lane >> 4;

  // XCD-chunked bijective swizzle (1024 % 8 == 0)
  int dd = blockIdx.x;
  int tileid = (dd & 7) * 128 + (dd >> 3);
  const int mtile = tileid >> 2;
  const int nc = tileid & 3;
  const int m0 = mtile * 256;
  const int n0 = nc * 256;
  const int b = m0 >> 12;

  // staging: per half-tile thread covers rows (tid>>3) and 64+(tid>>3),
  // phys slot tid&7; source col pre-swizzled (both-sides rule)
  const int r0 = tid >> 3;
  const int sl = tid & 7;
  const int c0 = ((sl ^ (r0 & 7)) << 3);
  const unsigned short* pA = hsb + (size_t)(m0 + r0) * D_DIM + c0;
  const unsigned short* pB = Wsb + (size_t)(n0 + r0) * D_DIM + c0;
  const int dst0 = tid * 8;
  const int dst1 = 4096 + tid * 8;

#define STG_A0(T)                                                     \
  do {                                                                \
    gload_lds16(lA + ((T)&1) * 16384 + dst0, pA + (T) * 64);          \
    gload_lds16(lA + ((T)&1) * 16384 + dst1, pA + 65536 + (T) * 64);  \
  } while (0)
#define STG_A1(T)                                                     \
  do {                                                                \
    gload_lds16(lA + ((T)&1) * 16384 + 8192 + dst0,                   \
                pA + 131072 + (T) * 64);                              \
    gload_lds16(lA + ((T)&1) * 16384 + 8192 + dst1,                   \
                pA + 131072 + 65536 + (T) * 64);                      \
  } while (0)
#define STG_B0(T)                                                     \
  do {                                                                \
    gload_lds16(lB + ((T)&1) * 16384 + dst0, pB + (T) * 64);          \
    gload_lds16(lB + ((T)&1) * 16384 + dst1, pB + 65536 + (T) * 64);  \
  } while (0)
#define STG_B1(T)                                                     \
  do {                                                                \
    gload_lds16(lB + ((T)&1) * 16384 + 8192 + dst0,                   \
                pB + 131072 + (T) * 64);                              \
    gload_lds16(lB + ((T)&1) * 16384 + 8192 + dst1,                   \
                pB + 131072 + 65536 + (T) * 64);                      \
  } while (0)

  // fragment bases (elements); XOR slot invariant across mi/ni (16-row steps)
  const int swz0 = ((lg ^ (l15 & 7)) << 3);        // kk=0
  const int swz1 = (((4 + lg) ^ (l15 & 7)) << 3);  // kk=1
  const int afix = wm * 8192 + l15 * 64;
  const int bfix = (wn >> 1) * 8192 + ((wn & 1) * 64 + l15) * 64;

  f32x4 acc[8][4];
#pragma unroll
  for (int i = 0; i < 8; ++i)
#pragma unroll
    for (int j = 0; j < 4; ++j) acc[i][j] = (f32x4){0.f, 0.f, 0.f, 0.f};

#define BAR() __builtin_amdgcn_s_barrier()
#define VM(N) asm volatile("s_waitcnt vmcnt(" #N ")" ::: "memory")

#define MM16(ACB, FA, FB)                                                  \
  {                                                                        \
    __builtin_amdgcn_s_setprio(1);                                         \
    _Pragma("unroll") for (int kk = 0; kk < 2; ++kk) {                     \
      _Pragma("unroll") for (int mi = 0; mi < 4; ++mi) {                   \
        _Pragma("unroll") for (int ni = 0; ni < 2; ++ni) {                 \
          ACB = __builtin_amdgcn_mfma_f32_16x16x32_bf16(                   \
              FA[kk * 4 + mi], FB[kk * 2 + ni], ACB, 0, 0, 0);             \
        }                                                                  \
      }                                                                    \
    }                                                                      \
    __builtin_amdgcn_s_setprio(0);                                         \
  }

#define TILE(T, S0, S1, S2, S3, WQ)                                        \
  {                                                                        \
    short8 fa_lo[8], fa_hi[8], fb_lo[4], fb_hi[4];                         \
    /* p0 */                                                               \
    _Pragma("unroll") for (int kk = 0; kk < 2; ++kk) {                     \
      const int sw = kk ? swz1 : swz0;                                     \
      _Pragma("unroll") for (int mi = 0; mi < 4; ++mi)                     \
          fa_lo[kk * 4 + mi] = *(const short8*)(lA + ((T)&1) * 16384 +     \
                                                afix + mi * 1024 + sw);    \
      _Pragma("unroll") for (int ni = 0; ni < 2; ++ni)                     \
          fb_lo[kk * 2 + ni] = *(const short8*)(lB + ((T)&1) * 16384 +     \
                                                bfix + ni * 1024 + sw);    \
    }                                                                      \
    S0;                                                                    \
    BAR();                                                                 \
    MM16(acc[mi][ni], fa_lo, fb_lo);                                       \
    BAR();                                                                 \
    /* p1 */                                                               \
    _Pragma("unroll") for (int kk = 0; kk < 2; ++kk) {                     \
      const int sw = kk ? swz1 : swz0;                                     \
      _Pragma("unroll") for (int mi = 0; mi < 4; ++mi)                     \
          fa_hi[kk * 4 + mi] = *(const short8*)(lA + ((T)&1) * 16384 +     \
                                                afix + 4096 + mi * 1024 +  \
                                                sw);                       \
    }                                                                      \
    S1;                                                                    \
    BAR();                                                                 \
    MM16(acc[4 + mi][ni], fa_hi, fb_lo);                                   \
    BAR();                                                                 \
    /* p2 */                                                               \
    _Pragma("unroll") for (int kk = 0; kk < 2; ++kk) {                     \
      const int sw = kk ? swz1 : swz0;                                     \
      _Pragma("unroll") for (int ni = 0; ni < 2; ++ni)                     \
          fb_hi[kk * 2 + ni] = *(const short8*)(lB + ((T)&1) * 16384 +     \
                                                bfix + 2048 + ni * 1024 +  \
                                                sw);                       \
    }                                                                      \
    S2;                                                                    \
    BAR();                                                                 \
    MM16(acc[4 + mi][2 + ni], fa_hi, fb_hi);                               \
    BAR();                                                                 \
    /* p3 */                                                               \
    S3;                                                                    \
    BAR();                                                                 \
    MM16(acc[mi][2 + ni], fa_lo, fb_hi);                                   \
    WQ;                                                                    \
    BAR();                                                                 \
  }

  // prologue: tile0 all 4 half-tiles + tile1 A0,A1; certify tile0
  STG_A0(0); STG_A1(0); STG_B0(0); STG_B1(0);
  STG_A0(1); STG_A1(1);
  VM(4);
  BAR();

  TILE(0, STG_B0(1), STG_B1(1), STG_A0(2), STG_A1(2), VM(4))
  TILE(1, STG_B0(2), STG_B1(2), STG_A0(3), STG_A1(3), VM(4))
  TILE(2, STG_B0(3), STG_B1(3), STG_A0(4), STG_A1(4), VM(4))
  TILE(3, STG_B0(4), STG_B1(4), STG_A0(5), STG_A1(5), VM(4))
  TILE(4, STG_B0(5), STG_B1(5), STG_A0(6), STG_A1(6), VM(4))
  TILE(5, STG_B0(6), STG_B1(6), STG_A0(7), STG_A1(7), VM(4))
  TILE(6, STG_B0(7), STG_B1(7), STG_A0(8), STG_A1(8), VM(4))
  TILE(7, STG_B0(8), STG_B1(8), STG_A0(9), STG_A1(9), VM(4))
  TILE(8, STG_B0(9), STG_B1(9), STG_A0(10), STG_A1(10), VM(4))
  TILE(9, STG_B0(10), STG_B1(10), STG_A0(11), STG_A1(11), VM(4))
  TILE(10, STG_B0(11), STG_B1(11), STG_A0(12), STG_A1(12), VM(4))
  TILE(11, STG_B0(12), STG_B1(12), STG_A0(13), STG_A1(13), VM(4))
  TILE(12, STG_B0(13), STG_B1(13), STG_A0(14), STG_A1(14), VM(4))
  TILE(13, STG_B0(14), STG_B1(14), STG_A0(15), STG_A1(15), VM(4))
  TILE(14, STG_B0(15), STG_B1(15), , , VM(0))
  TILE(15, , , , , )

#undef TILE
#undef MM16
#undef STG_A0
#undef STG_A1
#undef STG_B0
#undef STG_B1
#undef VM
#undef BAR

  // epilogue: tanh(acc + c)*We, reduce over this block's 256 columns
  float chv[4], whv[4];
#pragma unroll
  for (int ni = 0; ni < 4; ++ni) {
    int h = n0 + wn * 64 + ni * 16 + l15;
    chv[ni] = cvec[b * H_DIM + h];
    whv[ni] = We_w[h];
  }
#pragma unroll
  for (int mi = 0; mi < 8; ++mi)
#pragma unroll
    for (int r = 0; r < 4; ++r) {
      float s = 0.f;
#pragma unroll
      for (int ni = 0; ni < 4; ++ni)
        s += tanh_fast(acc[mi][ni][r] + chv[ni]) * whv[ni];
      s += __shfl_xor(s, 1);
      s += __shfl_xor(s, 2);
      s += __shfl_xor(s, 4);
      s += __shfl_xor(s, 8);
      if (l15 == 0) scorebuf[wn][wm * 128 + mi * 16 + lg * 4 + r] = s;
    }
  __syncthreads();
  if (tid < 256) {
    float s = scorebuf[0][tid] + scorebuf[1][tid] + scorebuf[2][tid] +
              scorebuf[3][tid];
    atomicAdd(&score[m0 + tid], s);
  }
}

// ---------- fallback GEMM (round-1 structure, fp32 A in-kernel cvt) ----------
__global__ __launch_bounds__(256) void score_gemm_fp32_kernel(
    const float* __restrict__ hs,
    const unsigned short* __restrict__ Wsb,
    const float* __restrict__ cvec,
    const float* __restrict__ We_w,
    float* __restrict__ score_part) {
  __shared__ __align__(16) unsigned short lA[128 * 64];
  __shared__ __align__(16) unsigned short lB[128 * 64];
  __shared__ float scorebuf[2][128];

  const int tid = threadIdx.x;
  const int lane = tid & 63;
  const int wave = tid >> 6;
  const int wr = wave >> 1;
  const int wc = wave & 1;
  const int mtile = blockIdx.x;
  const int gy = blockIdx.y;
  const int m0 = mtile * 128;
  const int b = mtile >> 5;
  const int l15 = lane & 15;
  const int lg = lane >> 4;

  float rowsum[4][4];
#pragma unroll
  for (int i = 0; i < 4; ++i)
#pragma unroll
    for (int j = 0; j < 4; ++j) rowsum[i][j] = 0.f;

  for (int ncq = gy * 4; ncq < gy * 4 + 4; ++ncq) {
    const int n0 = ncq * 128;
    f32x4 acc[4][4];
#pragma unroll
    for (int i = 0; i < 4; ++i)
#pragma unroll
      for (int j = 0; j < 4; ++j) acc[i][j] = (f32x4){0.f, 0.f, 0.f, 0.f};

    for (int k0 = 0; k0 < D_DIM; k0 += 64) {
#pragma unroll
      for (int r = 0; r < 4; ++r) {
        int s = tid + r * 256;
        int row = s >> 3, slx = s & 7;
        int src = slx ^ (row & 7);
        gload_lds16(&lB[s * 8], Wsb + (size_t)(n0 + row) * D_DIM + k0 + src * 8);
      }
      float4 a0[4], a1[4];
#pragma unroll
      for (int r = 0; r < 4; ++r) {
        int s = tid + r * 256;
        int row = s >> 3, slx = s & 7;
        int src = slx ^ (row & 7);
        const float* ga = hs + (size_t)(m0 + row) * D_DIM + k0 + src * 8;
        a0[r] = *(const float4*)ga;
        a1[r] = *(const float4*)(ga + 4);
      }
#pragma unroll
      for (int r = 0; r < 4; ++r) {
        int s = tid + r * 256;
        union { unsigned short us[8]; short8 v; } pk;
        pk.us[0] = f2bf(a0[r].x); pk.us[1] = f2bf(a0[r].y);
        pk.us[2] = f2bf(a0[r].z); pk.us[3] = f2bf(a0[r].w);
        pk.us[4] = f2bf(a1[r].x); pk.us[5] = f2bf(a1[r].y);
        pk.us[6] = f2bf(a1[r].z); pk.us[7] = f2bf(a1[r].w);
        *(short8*)(&lA[s * 8]) = pk.v;
      }
      __syncthreads();
#pragma unroll
      for (int kf = 0; kf < 2; ++kf) {
        short8 af[4], bfr[4];
        int cgrp = kf * 4 + lg;
#pragma unroll
        for (int mi = 0; mi < 4; ++mi) {
          int row = wr * 64 + mi * 16 + l15;
          af[mi] = *(const short8*)&lA[row * 64 + (cgrp ^ (row & 7)) * 8];
        }
#pragma unroll
        for (int ni = 0; ni < 4; ++ni) {
          int row = wc * 64 + ni * 16 + l15;
          bfr[ni] = *(const short8*)&lB[row * 64 + (cgrp ^ (row & 7)) * 8];
        }
#pragma unroll
        for (int mi = 0; mi < 4; ++mi)
#pragma unroll
          for (int ni = 0; ni < 4; ++ni)
            acc[mi][ni] = __builtin_amdgcn_mfma_f32_16x16x32_bf16(
                af[mi], bfr[ni], acc[mi][ni], 0, 0, 0);
      }
      __syncthreads();
    }
#pragma unroll
    for (int ni = 0; ni < 4; ++ni) {
      int h = n0 + wc * 64 + ni * 16 + l15;
      float ch = cvec[b * H_DIM + h];
      float wh = We_w[h];
#pragma unroll
      for (int mi = 0; mi < 4; ++mi)
#pragma unroll
        for (int r2 = 0; r2 < 4; ++r2)
          rowsum[mi][r2] += tanh_fast(acc[mi][ni][r2] + ch) * wh;
    }
  }
#pragma unroll
  for (int mi = 0; mi < 4; ++mi)
#pragma unroll
    for (int r2 = 0; r2 < 4; ++r2) {
      float v = rowsum[mi][r2];
      v += __shfl_xor(v, 1);
      v += __shfl_xor(v, 2);
      v += __shfl_xor(v, 4);
      v += __shfl_xor(v, 8);
      rowsum[mi][r2] = v;
    }
  if (l15 == 0) {
#pragma unroll
    for (int mi = 0; mi < 4; ++mi)
#pragma unroll
      for (int r2 = 0; r2 < 4; ++r2)
        scorebuf[wc][wr * 64 + mi * 16 + lg * 4 + r2] = rowsum[mi][r2];
  }
  __syncthreads();
  if (tid < 128) {
    score_part[(size_t)gy * M_TOT + m0 + tid] =
        scorebuf[0][tid] + scorebuf[1][tid];
  }
}

// ---------- softmax (single combined score buffer), 1024 thr/block ---------
__global__ __launch_bounds__(1024) void softmax1_kernel(
    const float* __restrict__ score,
    const int* __restrict__ hs_i,
    const int* __restrict__ ht_i,
    const float* __restrict__ emb,
    const float* __restrict__ lam,
    float* __restrict__ wout) {
  int b = blockIdx.x;
  int tid = threadIdx.x;
  int wave = tid >> 6;
  int lane = tid & 63;
  float lam0 = lam[0], lam1 = lam[1], lam2 = lam[2];
  int tk = ht_i[b];
  float xs[4];
  float mx = -1e30f;
#pragma unroll
  for (int i = 0; i < 4; ++i) {
    int s = tid + i * 1024;
    size_t m = (size_t)b * S_LEN + s;
    float x = score[m];
    int idx = hs_i[m] * 512 + tk;
    const float* e = emb + (size_t)idx * 3;
    x += e[0] * lam0 + e[1] * lam1 + e[2] * lam2;
    xs[i] = x;
    mx = fmaxf(mx, x);
  }
  __shared__ float redm[16];
  __shared__ float reds[16];
#pragma unroll
  for (int off = 32; off >= 1; off >>= 1) mx = fmaxf(mx, __shfl_xor(mx, off));
  if (lane == 0) redm[wave] = mx;
  __syncthreads();
  mx = redm[0];
#pragma unroll
  for (int w = 1; w < 16; ++w) mx = fmaxf(mx, redm[w]);
  float sum = 0.f;
#pragma unroll
  for (int i = 0; i < 4; ++i) {
    xs[i] = __expf(xs[i] - mx);
    sum += xs[i];
  }
#pragma unroll
  for (int off = 32; off >= 1; off >>= 1) sum += __shfl_xor(sum, off);
  if (lane == 0) reds[wave] = sum;
  __syncthreads();
  sum = 0.f;
#pragma unroll
  for (int w = 0; w < 16; ++w) sum += reds[w];
  float inv = 1.0f / sum;
#pragma unroll
  for (int i = 0; i < 4; ++i)
    wout[(size_t)b * S_LEN + tid + i * 1024] = xs[i] * inv;
}

// ---------- softmax for fallback path (NP partials) ----------
template <int NP>
__global__ void softmax_kernel(const float* __restrict__ part,
                               const int* __restrict__ hs_i,
                               const int* __restrict__ ht_i,
                               const float* __restrict__ emb,
                               const float* __restrict__ lam,
                               float* __restrict__ wout) {
  int b = blockIdx.x;
  int tid = threadIdx.x;
  float lam0 = lam[0], lam1 = lam[1], lam2 = lam[2];
  int tk = ht_i[b];
  float xs[16];
  float mx = -1e30f;
#pragma unroll
  for (int i = 0; i < 16; ++i) {
    int s = tid + i * 256;
    size_t m = (size_t)b * S_LEN + s;
    float x = 0.f;
#pragma unroll
    for (int g = 0; g < NP; ++g) x += part[(size_t)g * M_TOT + m];
    int idx = hs_i[m] * 512 + tk;
    const float* e = emb + (size_t)idx * 3;
    x += e[0] * lam0 + e[1] * lam1 + e[2] * lam2;
    xs[i] = x;
    mx = fmaxf(mx, x);
  }
  __shared__ float redm[4];
  __shared__ float reds[4];
#pragma unroll
  for (int off = 32; off >= 1; off >>= 1) mx = fmaxf(mx, __shfl_xor(mx, off));
  if ((tid & 63) == 0) redm[tid >> 6] = mx;
  __syncthreads();
  mx = fmaxf(fmaxf(redm[0], redm[1]), fmaxf(redm[2], redm[3]));
  float sum = 0.f;
#pragma unroll
  for (int i = 0; i < 16; ++i) {
    xs[i] = __expf(xs[i] - mx);
    sum += xs[i];
  }
#pragma unroll
  for (int off = 32; off >= 1; off >>= 1) sum += __shfl_xor(sum, off);
  if ((tid & 63) == 0) reds[tid >> 6] = sum;
  __syncthreads();
  sum = reds[0] + reds[1] + reds[2] + reds[3];
  float inv = 1.0f / sum;
#pragma unroll
  for (int i = 0; i < 16; ++i)
    wout[(size_t)b * S_LEN + tid + i * 256] = xs[i] * inv;
}

// ---------- wsum (bf16 input) ----------
__global__ void wsum_bf16_kernel(const unsigned short* __restrict__ hsb,
                                 const float* __restrict__ w,
                                 float* __restrict__ u) {
  int bx = blockIdx.x;
  int b = bx >> 5;
  int sc = bx & 31;
  int tid = threadIdx.x;
  int dcol = tid * 4;
  int s0 = sc * 128;
  const unsigned short* base = hsb + ((size_t)b * S_LEN + s0) * D_DIM + dcol;
  const float* wrow = w + (size_t)b * S_LEN + s0;
  float4 acc = {0.f, 0.f, 0.f, 0.f};
#pragma unroll 4
  for (int i = 0; i < 128; ++i) {
    float ww = wrow[i];
    ushort2 v01 = *(const ushort2*)(base + (size_t)i * D_DIM);
    ushort2 v23 = *(const ushort2*)(base + (size_t)i * D_DIM + 2);
    acc.x += ww * __uint_as_float((unsigned int)v01.x << 16);
    acc.y += ww * __uint_as_float((unsigned int)v01.y << 16);
    acc.z += ww * __uint_as_float((unsigned int)v23.x << 16);
    acc.w += ww * __uint_as_float((unsigned int)v23.y << 16);
  }
  atomicAdd(&u[b * D_DIM + dcol + 0], acc.x);
  atomicAdd(&u[b * D_DIM + dcol + 1], acc.y);
  atomicAdd(&u[b * D_DIM + dcol + 2], acc.z);
  atomicAdd(&u[b * D_DIM + dcol + 3], acc.w);
}

// ---------- wsum (fp32 fallback) ----------
__global__ void wsum_kernel(const float* __restrict__ hs,
                            const float* __restrict__ w,
                            float* __restrict__ u) {
  int bx = blockIdx.x;
  int b = bx >> 5;
  int sc = bx & 31;
  int tid = threadIdx.x;
  int dcol = tid * 4;
  int s0 = sc * 128;
  const float* base = hs + ((size_t)b * S_LEN + s0) * D_DIM + dcol;
  const float* wrow = w + (size_t)b * S_LEN + s0;
  float4 acc = {0.f, 0.f, 0.f, 0.f};
#pragma unroll 4
  for (int i = 0; i < 128; ++i) {
    float ww = wrow[i];
    float4 v = *(const float4*)(base + (size_t)i * D_DIM);
    acc.x += ww * v.x;
    acc.y += ww * v.y;
    acc.z += ww * v.z;
    acc.w += ww * v.w;
  }
  atomicAdd(&u[b * D_DIM + dcol + 0], acc.x);
  atomicAdd(&u[b * D_DIM + dcol + 1], acc.y);
  atomicAdd(&u[b * D_DIM + dcol + 2], acc.z);
  atomicAdd(&u[b * D_DIM + dcol + 3], acc.w);
}

// ---------- alpha[b,h] = u[b]·Ws_w[h] + Ws_b[h] ----------
__global__ void alpha_kernel(const float* __restrict__ u,
                             const float* __restrict__ Ws_w,
                             const float* __restrict__ Ws_b,
                             float* __restrict__ out) {
  int gw = blockIdx.x * 4 + (threadIdx.x >> 6);
  int lane = threadIdx.x & 63;
  int b = gw >> 10;
  int h = gw & 1023;
  const float* ur = u + b * D_DIM;
  const float* wrow = Ws_w + (size_t)h * D_DIM;
  float acc = 0.f;
#pragma unroll
  for (int i = 0; i < 4; ++i) {
    int dcol = lane * 4 + i * 256;
    float4 x = *(const float4*)(ur + dcol);
    float4 y = *(const float4*)(wrow + dcol);
    acc += x.x * y.x + x.y * y.y + x.z * y.z + x.w * y.w;
  }
#pragma unroll
  for (int off = 32; off >= 1; off >>= 1) acc += __shfl_xor(acc, off);
  if (lane == 0) out[b * H_DIM + h] = acc + Ws_b[h];
}

extern "C" void kernel_launch(void* const* d_in, const int* in_sizes, int n_in,
                              void* d_out, int out_size, void* d_ws,
                              size_t ws_size, hipStream_t stream) {
  const float* hs = (const float*)d_in[0];
  const float* ht_k = (const float*)d_in[1];
  const float* hm_k = (const float*)d_in[2];
  const float* Ws_w = (const float*)d_in[3];
  const float* Ws_b = (const float*)d_in[4];
  const float* Wt_w = (const float*)d_in[5];
  const float* Wt_b = (const float*)d_in[6];
  const float* Wr_w = (const float*)d_in[7];
  const float* Wr_b = (const float*)d_in[8];
  const float* We_w = (const float*)d_in[9];
  const float* emb = (const float*)d_in[11];
  const float* lam = (const float*)d_in[12];
  const int* hs_i = (const int*)d_in[13];
  const int* ht_i = (const int*)d_in[14];
  float* out = (float*)d_out;

  const size_t HSB = (size_t)M_TOT * D_DIM * 2;  // 128 MB
  // fast layout: [hsb][Wsb 2M][score 256K][u 64K][wgt 256K][cvec 64K]
  const size_t FAST_NEEDED =
      HSB + 2097152 + 262144 + 65536 + 262144 + 65536;

  char* ws = (char*)d_ws;
  if (ws_size >= FAST_NEEDED) {
    unsigned short* hsb = (unsigned short*)ws;
    unsigned short* Wsb = (unsigned short*)(ws + HSB);
    float* score = (float*)(ws + HSB + 2097152);
    float* u = (float*)(ws + HSB + 2097152 + 262144);
    float* wgt = (float*)(ws + HSB + 2097152 + 262144 + 65536);
    float* cvec = (float*)(ws + HSB + 2097152 + 262144 + 65536 + 262144);

    hipFuncSetAttribute((const void*)score_gemm10_kernel,
                        hipFuncAttributeMaxDynamicSharedMemorySize, 131072);

    cvt_hs_kernel<<<32768, 256, 0, stream>>>(hs, hsb);
    prep_fused_kernel<<<4608, 256, 0, stream>>>(Ws_w, Wsb, ht_k, hm_k, Wt_w,
                                                Wt_b, Wr_w, Wr_b, cvec);
    // zero score + u in one pass (adjacent in layout)
    hipMemsetAsync(score, 0, 262144 + 65536, stream);
    score_gemm10_kernel<<<1024, 512, 131072, stream>>>(hsb, Wsb, cvec, We_w,
                                                       score);
    softmax1_kernel<<<16, 1024, 0, stream>>>(score, hs_i, ht_i, emb, lam,
                                             wgt);
    wsum_bf16_kernel<<<512, 256, 0, stream>>>(hsb, wgt, u);
    alpha_kernel<<<4096, 256, 0, stream>>>(u, Ws_w, Ws_b, out);
    return;
  }

  // fallback: small-ws path
  unsigned short* Wsb = (unsigned short*)(ws);
  float* cvec = (float*)(ws + 2097152);
  float* part = (float*)(ws + 2097152 + 65536);
  float* wgt = (float*)(ws + 2097152 + 65536 + 524288);
  float* u = (float*)(ws + 2097152 + 65536 + 524288 + 262144);

  prep_fused_kernel<<<4608, 256, 0, stream>>>(Ws_w, Wsb, ht_k, hm_k, Wt_w,
                                              Wt_b, Wr_w, Wr_b, cvec);
  dim3 g2(512, 2);
  score_gemm_fp32_kernel<<<g2, 256, 0, stream>>>(hs, Wsb, cvec, We_w, part);
  softmax_kernel<2><<<16, 256, 0, stream>>>(part, hs_i, ht_i, emb, lam, wgt);
  hipMemsetAsync(u, 0, B_SZ * D_DIM * sizeof(float), stream);
  wsum_kernel<<<512, 256, 0, stream>>>(hs, wgt, u);
  alpha_kernel<<<4096, 256, 0, stream>>>(u, Ws_w, Ws_b, out);
}